// Round 3
// baseline (3267.846 us; speedup 1.0000x reference)
//
#include <hip/hip_runtime.h>
#include <math.h>

#define BB 128
#define QQ 200
#define CC 92
#define NP1 201  // n+1 (1-based columns/rows, index 0 = sentinel)

// ---------------------------------------------------------------------------
// Kernel 1: lse[b,i] = logsumexp(pred_cat[b,i,:]) over C=92 classes
// ---------------------------------------------------------------------------
__global__ void lse_kernel(const float* __restrict__ pc, float* __restrict__ lse) {
    int idx = blockIdx.x * blockDim.x + threadIdx.x;  // over B*Q
    if (idx >= BB * QQ) return;
    const float* row = pc + (size_t)idx * CC;
    float m = -INFINITY;
    for (int c = 0; c < CC; ++c) m = fmaxf(m, row[c]);
    float s = 0.f;
    for (int c = 0; c < CC; ++c) s += expf(row[c] - m);
    lse[idx] = m + logf(s);
}

// ---------------------------------------------------------------------------
// Kernel 2: cost[b,i,j] = CE + SmoothL1*mask
// ---------------------------------------------------------------------------
__global__ void cost_kernel(const float* __restrict__ pc,
                            const float* __restrict__ pb,
                            const int*   __restrict__ tc,
                            const float* __restrict__ tb,
                            const float* __restrict__ lse,
                            float* __restrict__ cost) {
    long idx = blockIdx.x * (long)blockDim.x + threadIdx.x;
    if (idx >= (long)BB * QQ * QQ) return;
    int j = (int)(idx % QQ);
    int i = (int)((idx / QQ) % QQ);
    int b = (int)(idx / ((long)QQ * QQ));
    int cls = tc[b * QQ + j];
    float ce = lse[b * QQ + i] - pc[((size_t)(b * QQ + i)) * CC + cls];
    const float* pbb = pb + ((size_t)(b * QQ + i)) * 4;
    const float* tbb = tb + ((size_t)(b * QQ + j)) * 4;
    float sl1 = 0.f;
#pragma unroll
    for (int k = 0; k < 4; ++k) {
        float d = pbb[k] - tbb[k];
        float ad = fabsf(d);
        sl1 += (ad < 1.f) ? 0.5f * d * d : (ad - 0.5f);
    }
    float mask = (cls != 0) ? 1.f : 0.f;
    cost[idx] = ce + sl1 * mask;
}

// ---------------------------------------------------------------------------
// order-preserving float -> uint mapping (for exact lexicographic argmin)
// ---------------------------------------------------------------------------
__device__ __forceinline__ unsigned sortable(float f) {
    unsigned u = __float_as_uint(f);
    return u ^ ((unsigned)((int)u >> 31) | 0x80000000u);
}
__device__ __forceinline__ float unsortable(unsigned hi) {
    unsigned fb = (hi & 0x80000000u) ? (hi ^ 0x80000000u) : ~hi;
    return __uint_as_float(fb);
}

// ---------------------------------------------------------------------------
// Kernel 3: Hungarian (JV shortest augmenting path) — one 64-lane wave per
// batch. NEW vs round 2: JV initialization (column reduction v[j]=min_i C,
// row reduction u[i]=min_j(C-v), greedy matching on tight edges) so only the
// remaining free rows run Dijkstra phases, starting from tight duals.
// Init satisfies r = C-u-v >= 0 and matched edges tight => each SAP phase is
// exact; result is the optimal assignment (same as reference's optimum).
// Phase loop is verbatim from the verified round-2 kernel.
// Lane t owns columns jc = 1+t+64k (k=0..3; k=3 only for t<8).
// ---------------------------------------------------------------------------
__global__ __launch_bounds__(64) void hungarian_kernel(const float* __restrict__ cost,
                                                       float* __restrict__ out) {
    const int b = blockIdx.x;
    const int t = threadIdx.x;
    const float* cb = cost + (size_t)b * QQ * QQ;

    __shared__ float u[NP1];
    __shared__ int   p[NP1];     // p[c] = row matched to column c (1-based), 0 = free
    __shared__ int   wayl[NP1];
    __shared__ int   rowm[NP1];  // rowm[i] = 1 if row i matched by greedy init

    const float INF = 1e9f;
    const int nval = (t < 8) ? 4 : 3;   // slot k valid iff 1+t+64k <= 200

    for (int j = t; j < NP1; j += 64) p[j] = 0;

    // ---- column reduction: v[j] = min_i C[i,j] (register, per-lane slots)
    float v[4] = {INF, INF, INF, INF};
    for (int i = 0; i < QQ; ++i) {
        const float* r = cb + (size_t)i * QQ;
        v[0] = fminf(v[0], r[t]);
        v[1] = fminf(v[1], r[64 + t]);
        v[2] = fminf(v[2], r[128 + t]);
        if (t < 8) v[3] = fminf(v[3], r[192 + t]);
    }

    // ---- row reduction + greedy matching on tight edges
    // key = sortable(C-v)<<32 | matchedflag<<30 | jc : min value first, then
    // prefer unmatched, then smallest column.
    int mcols = 0;  // bit k set if owned column slot k already matched
    for (int i = 1; i <= QQ; ++i) {
        const float* crow = cb + (size_t)(i - 1) * QQ;
        unsigned long long key = ~0ULL;
#pragma unroll
        for (int k = 0; k < 4; ++k) {
            if (k < nval) {
                int jc = 1 + t + 64 * k;
                float rc = crow[t + 64 * k] - v[k];
                unsigned long long kk = ((unsigned long long)sortable(rc) << 32)
                    | (unsigned)((mcols & (1 << k)) ? 0x40000000u : 0u) | (unsigned)jc;
                key = (kk < key) ? kk : key;
            }
        }
#pragma unroll
        for (int off = 32; off > 0; off >>= 1) {
            unsigned long long o = (unsigned long long)__shfl_xor((long long)key, off, 64);
            key = (o < key) ? o : key;
        }
        float m = unsortable((unsigned)(key >> 32));
        int jsel = (int)(key & 0xffffu);
        int gotfree = !(key & 0x40000000u);
        if (t == 0) {
            u[i] = m;                // row dual: feasibility r>=0 for all j
            rowm[i] = gotfree;       // matched iff tight unmatched col existed
            if (gotfree) p[jsel] = i;
        }
        if (gotfree && ((jsel - 1) & 63) == t) mcols |= 1 << ((jsel - 1) >> 6);
    }

    // ---- SAP phases for remaining free rows (verbatim round-2 loop)
    float minv[4];
    int   waysl[4];
    int   prow[4];
    int   usedm;

    for (int i = 1; i <= QQ; ++i) {
        if (rowm[i]) continue;      // already matched by greedy init
        if (t == 0) p[0] = i;       // sentinel: augmentation's final step reads p[0]
        minv[0] = minv[1] = minv[2] = minv[3] = INF;
        waysl[0] = waysl[1] = waysl[2] = waysl[3] = 0;
        usedm = 0;
        int j0 = 0;
        int i0 = i;
        for (;;) {
            if (j0 > 0) {
                int s = (j0 - 1) >> 6;
                if (((j0 - 1) & 63) == t) { usedm |= 1 << s; prow[s] = i0; }
            }

            float u0 = u[i0];                       // LDS broadcast read
            const float* crow = cb + (size_t)(i0 - 1) * QQ;
            float c[4];
            c[0] = crow[t];
            c[1] = crow[64 + t];
            c[2] = crow[128 + t];
            c[3] = (t < 8) ? crow[192 + t] : 0.f;

            unsigned long long key = ~0ULL;
#pragma unroll
            for (int k = 0; k < 4; ++k) {
                int jc = 1 + t + 64 * k;
                bool active = (k < nval) && !(usedm & (1 << k));
                if (active) {
                    float cur = c[k] - u0 - v[k];          // (C - u) - v
                    if (cur < minv[k]) { minv[k] = cur; waysl[k] = j0; }
                    unsigned long long kk =
                        ((unsigned long long)sortable(minv[k]) << 32) | (unsigned)jc;
                    key = (kk < key) ? kk : key;
                }
            }
#pragma unroll
            for (int off = 32; off > 0; off >>= 1) {
                unsigned long long o =
                    (unsigned long long)__shfl_xor((long long)key, off, 64);
                key = (o < key) ? o : key;
            }
            int j1 = (int)(key & 0xffffffffu);
            float delta = unsortable((unsigned)(key >> 32));

#pragma unroll
            for (int k = 0; k < 4; ++k) {
                if (usedm & (1 << k)) {
                    v[k] -= delta;
                    atomicAdd(&u[prow[k]], delta);   // ds_add_f32, rows distinct
                } else if (k < nval) {
                    minv[k] -= delta;
                }
            }
            if (t == 0) atomicAdd(&u[i], delta);     // sentinel column 0 (p[0]=i)

            {
                int s = (j1 - 1) >> 6;
                if (((j1 - 1) & 63) == t) wayl[j1] = waysl[s];
            }

            int pi = p[j1];                          // LDS broadcast read
            if (pi == 0) { j0 = j1; break; }
            j0 = j1; i0 = pi;
        }
        // augment: flip matching along alternating path (lane 0, sequential)
        if (t == 0) {
            int jj = j0;
            while (jj != 0) { int jn = wayl[jj]; p[jj] = p[jn]; jj = jn; }
        }
    }

    // p[j] = row matched to column j (1-based); emit per-row matched cost
    for (int j = 1 + t; j <= QQ; j += 64) {
        int row = p[j] - 1;
        out[b * QQ + row] = cb[(size_t)row * QQ + (j - 1)];
    }
}

// ---------------------------------------------------------------------------
extern "C" void kernel_launch(void* const* d_in, const int* in_sizes, int n_in,
                              void* d_out, int out_size, void* d_ws, size_t ws_size,
                              hipStream_t stream) {
    const float* pred_cat  = (const float*)d_in[0];
    const float* pred_bbox = (const float*)d_in[1];
    const int*   tar_cat   = (const int*)d_in[2];
    const float* tar_bbox  = (const float*)d_in[3];
    float* out = (float*)d_out;

    float* cost = (float*)d_ws;                     // B*Q*Q floats = 20.48 MB
    float* lse  = cost + (size_t)BB * QQ * QQ;      // B*Q floats

    lse_kernel<<<(BB * QQ + 255) / 256, 256, 0, stream>>>(pred_cat, lse);
    cost_kernel<<<((long)BB * QQ * QQ + 255) / 256, 256, 0, stream>>>(
        pred_cat, pred_bbox, tar_cat, tar_bbox, lse, cost);
    hungarian_kernel<<<BB, 64, 0, stream>>>(cost, out);
}

// Round 5
// 1979.306 us; speedup vs baseline: 1.6510x; 1.6510x over previous
//
#include <hip/hip_runtime.h>
#include <math.h>

#define BB 128
#define QQ 200
#define CC 92
#define NP1 201              // n+1 (1-based columns/rows, index 0 = sentinel)
#define CMPAD (QQ * QQ + 64) // +64 pad so unconditional c3 load stays in-bounds

// ---------------------------------------------------------------------------
// Kernel 1: lse[b,i] = logsumexp(pred_cat[b,i,:]) over C=92 classes
// ---------------------------------------------------------------------------
__global__ void lse_kernel(const float* __restrict__ pc, float* __restrict__ lse) {
    int idx = blockIdx.x * blockDim.x + threadIdx.x;  // over B*Q
    if (idx >= BB * QQ) return;
    const float* row = pc + (size_t)idx * CC;
    float m = -INFINITY;
    for (int c = 0; c < CC; ++c) m = fmaxf(m, row[c]);
    float s = 0.f;
    for (int c = 0; c < CC; ++c) s += expf(row[c] - m);
    lse[idx] = m + logf(s);
}

// ---------------------------------------------------------------------------
// Kernel 2: cost[b,i,j] = CE + SmoothL1*mask
// ---------------------------------------------------------------------------
__global__ void cost_kernel(const float* __restrict__ pc,
                            const float* __restrict__ pb,
                            const int*   __restrict__ tc,
                            const float* __restrict__ tb,
                            const float* __restrict__ lse,
                            float* __restrict__ cost) {
    long idx = blockIdx.x * (long)blockDim.x + threadIdx.x;
    if (idx >= (long)BB * QQ * QQ) return;
    int j = (int)(idx % QQ);
    int i = (int)((idx / QQ) % QQ);
    int b = (int)(idx / ((long)QQ * QQ));
    int cls = tc[b * QQ + j];
    float ce = lse[b * QQ + i] - pc[((size_t)(b * QQ + i)) * CC + cls];
    const float* pbb = pb + ((size_t)(b * QQ + i)) * 4;
    const float* tbb = tb + ((size_t)(b * QQ + j)) * 4;
    float sl1 = 0.f;
#pragma unroll
    for (int k = 0; k < 4; ++k) {
        float d = pbb[k] - tbb[k];
        float ad = fabsf(d);
        sl1 += (ad < 1.f) ? 0.5f * d * d : (ad - 0.5f);
    }
    float mask = (cls != 0) ? 1.f : 0.f;
    cost[idx] = ce + sl1 * mask;
}

// ---------------------------------------------------------------------------
// order-preserving float -> uint mapping (exact lexicographic argmin)
// ---------------------------------------------------------------------------
__device__ __forceinline__ unsigned sortable(float f) {
    unsigned u = __float_as_uint(f);
    return u ^ ((unsigned)((int)u >> 31) | 0x80000000u);
}
__device__ __forceinline__ float unsortable(unsigned hi) {
    unsigned fb = (hi & 0x80000000u) ? (hi ^ 0x80000000u) : ~hi;
    return __uint_as_float(fb);
}
__device__ __forceinline__ unsigned umin_(unsigned a, unsigned b) { return a < b ? a : b; }

// wave64 min-reduce via DPP (row_shr 1/2/4/8, row_bcast 15/31), result
// broadcast from lane 63 as an SGPR. bound_ctrl=false + old=x => invalid
// source lanes keep x. ~10x lower latency than a ds_bpermute butterfly.
__device__ __forceinline__ unsigned wave_umin_bcast(unsigned x) {
    unsigned y;
    y = (unsigned)__builtin_amdgcn_update_dpp((int)x, (int)x, 0x111, 0xf, 0xf, false); x = umin_(x, y);
    y = (unsigned)__builtin_amdgcn_update_dpp((int)x, (int)x, 0x112, 0xf, 0xf, false); x = umin_(x, y);
    y = (unsigned)__builtin_amdgcn_update_dpp((int)x, (int)x, 0x114, 0xf, 0xf, false); x = umin_(x, y);
    y = (unsigned)__builtin_amdgcn_update_dpp((int)x, (int)x, 0x118, 0xf, 0xf, false); x = umin_(x, y);
    y = (unsigned)__builtin_amdgcn_update_dpp((int)x, (int)x, 0x142, 0xf, 0xf, false); x = umin_(x, y);
    y = (unsigned)__builtin_amdgcn_update_dpp((int)x, (int)x, 0x143, 0xf, 0xf, false); x = umin_(x, y);
    return (unsigned)__builtin_amdgcn_readlane((int)x, 63);
}

// ---------------------------------------------------------------------------
// Kernel 3: Hungarian (e-maxx JV, round-2 trajectory bit-for-bit) — one
// 64-lane wave per batch.
//  - cost matrix staged in LDS (157 KiB static; gfx950 LDS/CU = 160 KiB)
//  - argmin: DPP wave-min on sortable(minv) + per-slot ballots (k-major,
//    then lowest lane = smallest j — exact jnp.argmin tie-break)
//  - p[] and way[] in per-lane registers via v_readlane (uniform index)
//  - u[] in LDS: read is parallel with the row read; atomicAdd updates keep
//    reference bit-exact repeated += delta.
// BUGFIX vs round 4: minv/waysl updates gated on !used — a used column's
// way entry must FREEZE (round 4 let it keep mutating, corrupting the
// augmenting-path chain => cycle => hang).
// Lane t owns columns jc = 1+t+64k (k=0..3; k=3 valid only for t<8).
// ---------------------------------------------------------------------------
__global__ __launch_bounds__(64) void hungarian_kernel(const float* __restrict__ cost,
                                                       float* __restrict__ out) {
    const int b = blockIdx.x;
    const int t = threadIdx.x;
    const float* cb = cost + (size_t)b * QQ * QQ;

    __shared__ __align__(16) float cm[CMPAD];
    __shared__ float u[NP1];

    // stage cost matrix into LDS (float4; single wave => in-order DS ops,
    // compiler waitcnts cover the reg deps; no barrier needed)
    {
        const float4* src = (const float4*)cb;
        float4* dst = (float4*)cm;
        for (int idx = t; idx < QQ * QQ / 4; idx += 64) dst[idx] = src[idx];
    }
    for (int j = t; j < NP1; j += 64) u[j] = 0.f;

    const float INF = 1e9f;
    const int nval = (t < 8) ? 4 : 3;   // slot k valid iff 1+t+64k <= 200

    float v[4] = {0.f, 0.f, 0.f, 0.f};
    int   pslot[4] = {0, 0, 0, 0};      // p for owned columns (0 = free)
    float minv[4];
    int   waysl[4];
    int   prow[4];
    int   usedm;

    for (int i = 1; i <= QQ; ++i) {
        minv[0] = minv[1] = minv[2] = minv[3] = INF;
        waysl[0] = waysl[1] = waysl[2] = waysl[3] = 0;
        usedm = 0;
        int j0 = 0;
        int i0 = i;                     // p[0] = i (sentinel)
        for (;;) {
            // mark j0 used (owner lane); sentinel j0==0 handled by lane 0 below
            if (j0 > 0) {
                int s = (j0 - 1) >> 6;
                if (((j0 - 1) & 63) == t) { usedm |= 1 << s; prow[s] = i0; }
            }

            float u0 = u[i0];                         // LDS broadcast read
            const float* crow = cm + (i0 - 1) * QQ;   // LDS row
            float c0 = crow[t];
            float c1 = crow[64 + t];
            float c2 = crow[128 + t];
            float c3 = crow[192 + t];                 // pad makes this in-bounds

            unsigned kv0, kv1, kv2, kv3;
            {
                float cur;
                cur = c0 - u0 - v[0];
                if (!(usedm & 1) && cur < minv[0]) { minv[0] = cur; waysl[0] = j0; }
                kv0 = (usedm & 1) ? 0xFFFFFFFFu : sortable(minv[0]);
                cur = c1 - u0 - v[1];
                if (!(usedm & 2) && cur < minv[1]) { minv[1] = cur; waysl[1] = j0; }
                kv1 = (usedm & 2) ? 0xFFFFFFFFu : sortable(minv[1]);
                cur = c2 - u0 - v[2];
                if (!(usedm & 4) && cur < minv[2]) { minv[2] = cur; waysl[2] = j0; }
                kv2 = (usedm & 4) ? 0xFFFFFFFFu : sortable(minv[2]);
                cur = c3 - u0 - v[3];
                if (!(usedm & 8) && t < 8 && cur < minv[3]) { minv[3] = cur; waysl[3] = j0; }
                kv3 = ((usedm & 8) || t >= 8) ? 0xFFFFFFFFu : sortable(minv[3]);
            }

            unsigned gmin = wave_umin_bcast(umin_(umin_(kv0, kv1), umin_(kv2, kv3)));
            float delta = unsortable(gmin);

            // smallest j with minv==delta: k-major (j = 1+t+64k), lowest lane
            unsigned long long m0 = __ballot(kv0 == gmin);
            unsigned long long m1 = __ballot(kv1 == gmin);
            unsigned long long m2 = __ballot(kv2 == gmin);
            unsigned long long m3 = __ballot(kv3 == gmin);
            int j1;
            if (m0)      j1 = 1   + (int)__builtin_ctzll(m0);
            else if (m1) j1 = 65  + (int)__builtin_ctzll(m1);
            else if (m2) j1 = 129 + (int)__builtin_ctzll(m2);
            else         j1 = 193 + (int)__builtin_ctzll(m3);

            // updates (identical single-op sequence to reference)
#pragma unroll
            for (int k = 0; k < 4; ++k) {
                if (usedm & (1 << k)) {
                    v[k] -= delta;
                    atomicAdd(&u[prow[k]], delta);   // ds_add_f32, rows distinct
                } else if (k < nval) {
                    minv[k] -= delta;
                }
            }
            if (t == 0) atomicAdd(&u[i], delta);     // sentinel column 0 (p[0]=i)

            // p[j1] via register + readlane (j1 uniform)
            {
                int jm = j1 - 1, kk = jm >> 6, ln = jm & 63;
                int ps = (kk == 0) ? pslot[0] : (kk == 1) ? pslot[1]
                        : (kk == 2) ? pslot[2] : pslot[3];
                int pi = __builtin_amdgcn_readlane(ps, ln);
                if (pi == 0) { j0 = j1; break; }
                j0 = j1; i0 = pi;
            }
        }

        // augment: flip matching along alternating path (uniform walk, all
        // lanes execute; way/p served from registers via readlane).
        // waysl entries on the path are frozen (set at/before use, never
        // mutated after — guaranteed by the !used gate above).
        {
            int jj = j0;
            while (jj != 0) {
                int jm = jj - 1, km = jm >> 6, lm = jm & 63;
                int ws = (km == 0) ? waysl[0] : (km == 1) ? waysl[1]
                        : (km == 2) ? waysl[2] : waysl[3];
                int jn = __builtin_amdgcn_readlane(ws, lm);
                int pnew;
                if (jn == 0) {
                    pnew = i;                        // p[0] = i (sentinel)
                } else {
                    int jm2 = jn - 1, kn = jm2 >> 6, ln2 = jm2 & 63;
                    int ps = (kn == 0) ? pslot[0] : (kn == 1) ? pslot[1]
                            : (kn == 2) ? pslot[2] : pslot[3];
                    pnew = __builtin_amdgcn_readlane(ps, ln2);
                }
                if (((jj - 1) & 63) == t) pslot[(jj - 1) >> 6] = pnew;
                jj = jn;
            }
        }
    }

    // pslot[k] = row matched to owned column jc; emit per-row matched cost
#pragma unroll
    for (int k = 0; k < 4; ++k) {
        if (k < nval) {
            int jc = 1 + t + 64 * k;
            int row = pslot[k] - 1;
            out[b * QQ + row] = cm[row * QQ + (jc - 1)];
        }
    }
}

// ---------------------------------------------------------------------------
extern "C" void kernel_launch(void* const* d_in, const int* in_sizes, int n_in,
                              void* d_out, int out_size, void* d_ws, size_t ws_size,
                              hipStream_t stream) {
    const float* pred_cat  = (const float*)d_in[0];
    const float* pred_bbox = (const float*)d_in[1];
    const int*   tar_cat   = (const int*)d_in[2];
    const float* tar_bbox  = (const float*)d_in[3];
    float* out = (float*)d_out;

    float* cost = (float*)d_ws;                     // B*Q*Q floats = 20.48 MB
    float* lse  = cost + (size_t)BB * QQ * QQ;      // B*Q floats

    lse_kernel<<<(BB * QQ + 255) / 256, 256, 0, stream>>>(pred_cat, lse);
    cost_kernel<<<((long)BB * QQ * QQ + 255) / 256, 256, 0, stream>>>(
        pred_cat, pred_bbox, tar_cat, tar_bbox, lse, cost);
    hungarian_kernel<<<BB, 64, 0, stream>>>(cost, out);
}